// Round 10
// baseline (8848.766 us; speedup 1.0000x reference)
//
#include <hip/hip_runtime.h>
#include <math.h>

#define NG 256        // grid blocks (1 per CU; LDS-limited anyway)
#define NT 512        // threads per block
#define NLOGW 250     // logits blocks (32 vocab rows each)

// ---------------------------------------------------------------------------
// Mutable cross-block state: producers write via LLC-direct store (sc0 sc1).
// All buffers are WRITE-ONCE per launch (64-step versioned), so consumers use
// plain cached vector loads: first touch of any line is post-producing-
// barrier, and each kernel dispatch's AQL acquire invalidates L1/L2, so no
// stale line can exist. (Validated rounds 5-9.)
// ---------------------------------------------------------------------------
__device__ __forceinline__ void stc(float* p, float v) {
    __hip_atomic_store(p, v, __ATOMIC_RELAXED, __HIP_MEMORY_SCOPE_AGENT);
}

// Round-5 barrier (best measured): 16 arrival lines -> c1 -> go, throttled spin.
__device__ __forceinline__ void gbar(int* cnt, int epoch, int g, int tid) {
    __syncthreads();   // drains vmcnt: sc1 stores are at the coherence point
    if (tid == 0) {
        int* c0 = cnt + ((g & 15) << 5);
        int* c1 = cnt + 512;
        int* go = cnt + 576;
        int r = __hip_atomic_fetch_add(c0, 1, __ATOMIC_RELAXED,
                                       __HIP_MEMORY_SCOPE_AGENT);
        if (r == (epoch << 4) - 1) {
            int r2 = __hip_atomic_fetch_add(c1, 1, __ATOMIC_RELAXED,
                                            __HIP_MEMORY_SCOPE_AGENT);
            if (r2 == (epoch << 4) - 1)
                __hip_atomic_store(go, epoch, __ATOMIC_RELAXED,
                                   __HIP_MEMORY_SCOPE_AGENT);
        }
        int it = 0;
        while (__hip_atomic_load(go, __ATOMIC_RELAXED,
                                 __HIP_MEMORY_SCOPE_AGENT) < epoch)
            if (++it > 4) __builtin_amdgcn_s_sleep(8);
    }
    __syncthreads();
}

__device__ __forceinline__ void merge3(float& M, float& S, float& I,
                                       float m, float se, float ii) {
    if (m > M)       { S = S * expf(M - m) + se; M = m; I = ii; }
    else if (m == M) { S += se; if (ii < I) I = ii; }
    else             { S += se * expf(m - M); }
}

// ---------------------------------------------------------------------------
// Vv[b,t,a] = sum_d enc[b,t,d] * attn_V[a,d]   (one-time precompute)
// ---------------------------------------------------------------------------
__global__ __launch_bounds__(256) void k_vv(const float* __restrict__ enc,
                                            const float* __restrict__ attn_V,
                                            float* __restrict__ Vv) {
    int wg = blockIdx.x;
    int b = wg / 40, t0 = (wg % 40) * 15;
    int tid = threadIdx.x;
    __shared__ __align__(16) float encL[15][512];
    for (int i = tid; i < 15 * 512; i += 256) {
        int tl = i >> 9, d = i & 511;
        encL[tl][d] = enc[((size_t)(b * 600) + (t0 + tl)) * 512 + d];
    }
    __syncthreads();
    for (int half = 0; half < 2; ++half) {
        int a = tid + half * 256;
        const float4* wrow = reinterpret_cast<const float4*>(attn_V + (size_t)a * 512);
        float acc[15];
#pragma unroll
        for (int tl = 0; tl < 15; ++tl) acc[tl] = 0.f;
        for (int k = 0; k < 128; ++k) {
            float4 w = wrow[k];
#pragma unroll
            for (int tl = 0; tl < 15; ++tl) {
                float4 x = reinterpret_cast<const float4*>(&encL[tl][0])[k];
                acc[tl] += w.x * x.x + w.y * x.y + w.z * x.z + w.w * x.w;
            }
        }
        for (int tl = 0; tl < 15; ++tl)
            Vv[((size_t)(b * 600) + (t0 + tl)) * 512 + a] = acc[tl];
    }
}

// ---------------------------------------------------------------------------
// Persistent kernel: all 64 decode steps. Block g: bg = g&15 (batch),
// sc16 = g>>4 (its t-chunk / e-slice / a-chunk). LDS permanently holds the
// block's Vv slice (38 t-rows x 512) and enc slice (600 t x 32 e).
// ---------------------------------------------------------------------------
__global__ __launch_bounds__(NT, 1) void mega(
    const float* __restrict__ enc, const float* __restrict__ emb,
    const float* __restrict__ w_ih, const float* __restrict__ w_hh,
    const float* __restrict__ b_ih, const float* __restrict__ b_hh,
    const float* __restrict__ conv_w, const float* __restrict__ conv_b,
    const float* __restrict__ attn_W, const float* __restrict__ attn_fc_w,
    const float* __restrict__ attn_fc_b, const float* __restrict__ attn_b,
    const float* __restrict__ fc_w, const float* __restrict__ fc_b,
    const float* __restrict__ Vv, const float* __restrict__ Z,
    float* hv, float* cv, float* wqv, float* scv, float* awv, float* pav,
    float* logZ, int* cnt, float* dout)
{
    const int g = blockIdx.x;
    const int tid = threadIdx.x;
    const int bg = g & 15;
    const int sc16 = g >> 4;
    const int lane = tid & 63;
    int ep = 0;

    __shared__ __align__(16) float VvL[38 * 512];    // 77,824 B persistent
    __shared__ __align__(16) float encL2[600 * 32];  // 76,800 B persistent
    __shared__ __align__(16) float scr[600];         // pb / red16 / accW scratch
    __shared__ float tokf[16];
    __shared__ float wredM[8], wredS[8];

    // ---- one-time LDS residency fill ----
    const int t0 = sc16 * 38;
    for (int idx = tid; idx < 38 * 128; idx += NT) {          // float4 units
        int tl = idx >> 7, k4 = idx & 127;
        if (t0 + tl < 600)
            ((float4*)VvL)[idx] =
                ((const float4*)(Vv + ((size_t)bg * 600 + t0 + tl) * 512))[k4];
    }
    for (int idx = tid; idx < 600 * 8; idx += NT) {           // float4 units
        int t = idx >> 3, k4 = idx & 7;
        ((float4*)encL2)[idx] =
            ((const float4*)(enc + ((size_t)bg * 600 + t) * 512 + sc16 * 32))[k4];
    }
    // ---- persistent per-thread score-phase constants (a = lane + q*64) ----
    float cw0r[8], cw1r[8], cw2r[8], cbr[8], fwr[8];
#pragma unroll
    for (int q = 0; q < 8; ++q) {
        int a = lane + (q << 6);
        cw0r[q] = conv_w[a * 3];
        cw1r[q] = conv_w[a * 3 + 1];
        cw2r[q] = conv_w[a * 3 + 2];
        cbr[q]  = conv_b[a] + attn_b[a];
        fwr[q]  = attn_fc_w[a];
    }
    const float fcb = attn_fc_b[0];
    __syncthreads();

    for (int s = 0; s < 64; ++s) {
        const float* h_r   = (s == 0) ? Z         : hv + (size_t)(s - 1) * 8192;
        const float* ctx_r = (s == 0) ? Z + 8192  : cv + (size_t)(s - 1) * 8192;
        const float* aw_r  = (s == 0) ? Z + 16384 : awv + (size_t)(s - 1) * 9600;
        float* h_w   = hv  + (size_t)s * 8192;
        float* ctx_w = cv  + (size_t)s * 8192;
        float* aw_w  = awv + (size_t)s * 9600;
        float* wq_s  = wqv + (size_t)s * 8192;
        float* sc_s  = scv + (size_t)s * 9600;
        float* pa_w  = pav + (size_t)s * 16384;

        // ========== phase1: token finalize + GRU (2 h-indices/block) ==========
        {
            if (s == 0) {
                if (tid < 16) tokf[tid] = 1.0f;   // SOS
                __syncthreads();
            } else {
                const float* pa_r = pav + (size_t)(s - 1) * 16384;
                const int wv = tid >> 6;
                for (int b = wv; b < 16; b += 8) {
                    float M = -3.4e38f, S = 0.f, I = 0.f;
                    for (int q = 0; q < 4; ++q) {
                        int pw = lane + (q << 6);
                        if (pw < NLOGW) {
                            const float* r = pa_r + ((size_t)pw * 16 + b) * 4;
                            merge3(M, S, I, r[0], r[1], r[2]);
                        }
                    }
                    for (int off = 32; off; off >>= 1)
                        merge3(M, S, I, __shfl_xor(M, off, 64),
                               __shfl_xor(S, off, 64), __shfl_xor(I, off, 64));
                    if (lane == 0) {
                        tokf[b] = I;
                        if (g == 0) stc(&logZ[(s - 1) * 16 + b], M + logf(S));
                    }
                }
                __syncthreads();
            }
            // GRU: thread = (b = tid>>5, il = (tid>>4)&1, pr = tid&15)
            const int b  = tid >> 5;
            const int il = (tid >> 4) & 1;
            const int pr = tid & 15;
            const int i  = (g << 1) + il;
            const int tok = (int)tokf[b];
            float ar = 0.f, az = 0.f, axn = 0.f, ahn = 0.f;
#pragma unroll
            for (int pass = 0; pass < 3; ++pass) {
                const float* xsrc = (pass == 0) ? emb + (size_t)tok * 512
                                  : (pass == 1) ? ctx_r + (b << 9)
                                                : h_r + (b << 9);
                const float* wbase = (pass == 2) ? w_hh : w_ih;
                const size_t rl = (pass == 2) ? 512 : 1024;
                const int ko = (pass == 1) ? 512 : 0;
                const float4* xv = (const float4*)xsrc + (pr << 3);
                const float4* wr = (const float4*)(wbase + (size_t)i * rl + ko) + (pr << 3);
                const float4* wz = (const float4*)(wbase + (size_t)(512 + i) * rl + ko) + (pr << 3);
                const float4* wn = (const float4*)(wbase + (size_t)(1024 + i) * rl + ko) + (pr << 3);
                float s0 = 0.f, s1 = 0.f, s2 = 0.f;
#pragma unroll
                for (int k = 0; k < 8; ++k) {
                    float4 x = xv[k];
                    float4 a = wr[k]; s0 += a.x*x.x + a.y*x.y + a.z*x.z + a.w*x.w;
                    float4 c = wz[k]; s1 += c.x*x.x + c.y*x.y + c.z*x.z + c.w*x.w;
                    float4 d = wn[k]; s2 += d.x*x.x + d.y*x.y + d.z*x.z + d.w*x.w;
                }
                ar += s0; az += s1;
                if (pass < 2) axn += s2; else ahn += s2;
            }
#pragma unroll
            for (int off = 8; off; off >>= 1) {
                ar  += __shfl_xor(ar, off, 64);
                az  += __shfl_xor(az, off, 64);
                axn += __shfl_xor(axn, off, 64);
                ahn += __shfl_xor(ahn, off, 64);
            }
            if (pr == 0) {
                float sr  = ar + b_ih[i] + b_hh[i];
                float sz  = az + b_ih[512 + i] + b_hh[512 + i];
                float sxn = axn + b_ih[1024 + i];
                float shn = ahn + b_hh[1024 + i];
                float r = 1.f / (1.f + expf(-sr));
                float z = 1.f / (1.f + expf(-sz));
                float n = tanhf(sxn + r * shn);
                float hp = h_r[(b << 9) + i];
                stc(&h_w[(b << 9) + i], (1.f - z) * n + z * hp);
            }
        }
        gbar(cnt, ++ep, g, tid);   // h complete

        // ========== phase2: wq — block computes 32 a's for b=bg ==========
        {
            const int al = tid >> 4, ln = tid & 15;
            const int a = (sc16 << 5) + al;
            const float4* wr = (const float4*)(attn_W + (size_t)a * 512) + (ln << 3);
            const float4* hh = (const float4*)(h_w + (bg << 9)) + (ln << 3);
            float acc = 0.f;
#pragma unroll
            for (int k = 0; k < 8; ++k) {
                float4 w = wr[k], x = hh[k];
                acc += w.x*x.x + w.y*x.y + w.z*x.z + w.w*x.w;
            }
#pragma unroll
            for (int off = 8; off; off >>= 1) acc += __shfl_xor(acc, off, 64);
            if (ln == 0) stc(&wq_s[(bg << 9) + a], acc);
        }
        gbar(cnt, ++ep, g, tid);   // wq complete

        // ========== phase3: scores — b=bg, 38 t from LDS-resident Vv ==========
        {
            float wqr[8];
#pragma unroll
            for (int q = 0; q < 8; ++q)
                wqr[q] = wq_s[(bg << 9) + lane + (q << 6)];
            const int wv = tid >> 6;
            for (int tl = wv; tl < 38; tl += 8) {
                const int t = t0 + tl;
                if (t < 600) {
                    const float awm = (t > 0)   ? aw_r[bg * 600 + t - 1] : 0.f;
                    const float aw0 = aw_r[bg * 600 + t];
                    const float awp = (t < 599) ? aw_r[bg * 600 + t + 1] : 0.f;
                    const float* vv = VvL + tl * 512;
                    float acc = 0.f;
#pragma unroll
                    for (int q = 0; q < 8; ++q) {
                        const int a = lane + (q << 6);
                        float uu = wqr[q] + vv[a] + cbr[q]
                                 + cw0r[q] * awm + cw1r[q] * aw0 + cw2r[q] * awp;
                        acc += tanhf(uu) * fwr[q];
                    }
#pragma unroll
                    for (int off = 32; off; off >>= 1) acc += __shfl_xor(acc, off, 64);
                    if (lane == 0) stc(&sc_s[bg * 600 + t], acc + fcb);
                }
            }
        }
        gbar(cnt, ++ep, g, tid);   // scores complete

        // ========== phase4: softmax (redundant per block) + ctx e-slice ==========
        {
            float* pb = scr;
            float lm = -3.4e38f;
            for (int t = tid; t < 600; t += NT) {
                float v = sc_s[bg * 600 + t];
                pb[t] = v;
                lm = fmaxf(lm, v);
            }
#pragma unroll
            for (int off = 32; off; off >>= 1) lm = fmaxf(lm, __shfl_xor(lm, off, 64));
            if ((tid & 63) == 0) wredM[tid >> 6] = lm;
            __syncthreads();
            float M = wredM[0];
#pragma unroll
            for (int q = 1; q < 8; ++q) M = fmaxf(M, wredM[q]);
            float lsum = 0.f;
            for (int t = tid; t < 600; t += NT) {
                float e = expf(pb[t] - M);
                pb[t] = e;
                lsum += e;
            }
#pragma unroll
            for (int off = 32; off; off >>= 1) lsum += __shfl_xor(lsum, off, 64);
            if ((tid & 63) == 0) wredS[tid >> 6] = lsum;
            __syncthreads();
            float S = 0.f;
#pragma unroll
            for (int q = 0; q < 8; ++q) S += wredS[q];
            const float invS = 1.f / S;
            if (sc16 == 0)
                for (int t = tid; t < 600; t += NT) stc(&aw_w[bg * 600 + t], pb[t] * invS);
            const int tg = tid >> 5, l32 = tid & 31;
            float acc = 0.f;
            for (int t = tg; t < 600; t += 16)
                acc += pb[t] * encL2[t * 32 + l32];
            __syncthreads();                 // pb dead; alias scr as red16
            float* red16 = scr;
            red16[(tg << 5) + l32] = acc;
            __syncthreads();
            if (tg == 0) {
                float a2 = 0.f;
#pragma unroll
                for (int q = 0; q < 16; ++q) a2 += red16[(q << 5) + l32];
                stc(&ctx_w[(bg << 9) + (sc16 << 5) + l32], a2 * invS);
            }
        }
        gbar(cnt, ++ep, g, tid);   // ctx complete

        // ========== phase5: logits — 1 row/thread, x read from L2 ==========
        {
            const int bb = tid & 15, jj = tid >> 4;   // jj in [0,32)
            const int v = (g << 5) + jj;
            float M = -3.4e38f, S = 0.f, I = 0.f;
            if (g < NLOGW) {
                const float4* wrow = (const float4*)(fc_w + (size_t)v * 1024);
                const float4* xh = (const float4*)(h_w + (bb << 9));
                const float4* xc = (const float4*)(ctx_w + (bb << 9));
                float a0 = 0.f, a1 = 0.f;
#pragma unroll 4
                for (int k = 0; k < 128; ++k) {
                    float4 w = wrow[k], x = xh[k];
                    a0 += w.x*x.x + w.y*x.y + w.z*x.z + w.w*x.w;
                }
#pragma unroll 4
                for (int k = 0; k < 128; ++k) {
                    float4 w = wrow[128 + k], x = xc[k];
                    a1 += w.x*x.x + w.y*x.y + w.z*x.z + w.w*x.w;
                }
                float acc = a0 + a1 + fc_b[v];
                stc(dout + ((size_t)bb * 64 + s) * 8000 + v, acc);
                M = acc; S = 1.f; I = (float)v;
            }
            // reduce over the 4 jj values within each wave (lanes xor 16, 32)
            merge3(M, S, I, __shfl_xor(M, 16, 64), __shfl_xor(S, 16, 64),
                   __shfl_xor(I, 16, 64));
            merge3(M, S, I, __shfl_xor(M, 32, 64), __shfl_xor(S, 32, 64),
                   __shfl_xor(I, 32, 64));
            __syncthreads();                 // scr free
            if ((tid & 63) < 16 && g < NLOGW) {
                float* a3 = scr + (((tid >> 6) << 4) + bb) * 3;
                a3[0] = M; a3[1] = S; a3[2] = I;
            }
            __syncthreads();
            if (tid < 16 && g < NLOGW) {
                float M2 = -3.4e38f, S2 = 0.f, I2 = 0.f;
#pragma unroll
                for (int w8 = 0; w8 < 8; ++w8) {
                    const float* a3 = scr + ((w8 << 4) + tid) * 3;
                    merge3(M2, S2, I2, a3[0], a3[1], a3[2]);
                }
                float* pr = pa_w + ((size_t)g * 16 + tid) * 4;
                stc(pr, M2); stc(pr + 1, S2); stc(pr + 2, I2);
            }
        }
        gbar(cnt, ++ep, g, tid);   // partials complete
    }

    // ---- final logZ (s=63) ----
    if (g == 0) {
        const float* pa_r = pav + (size_t)63 * 16384;
        const int wv = tid >> 6;
        for (int b = wv; b < 16; b += 8) {
            float M = -3.4e38f, S = 0.f, I = 0.f;
            for (int q = 0; q < 4; ++q) {
                int pw = lane + (q << 6);
                if (pw < NLOGW) {
                    const float* r = pa_r + ((size_t)pw * 16 + b) * 4;
                    merge3(M, S, I, r[0], r[1], r[2]);
                }
            }
            for (int off = 32; off; off >>= 1)
                merge3(M, S, I, __shfl_xor(M, off, 64),
                       __shfl_xor(S, off, 64), __shfl_xor(I, off, 64));
            if (lane == 0) stc(&logZ[63 * 16 + b], M + logf(S));
        }
    }
    gbar(cnt, ++ep, g, tid);
    // ---- normalize: logp = logits - logZ (vectorized) ----
    for (int r = g; r < 1024; r += NG) {          // r = b*64 + s
        float z = logZ[(r & 63) * 16 + (r >> 6)];
        float4* o = (float4*)(dout + (size_t)r * 8000);
        for (int i = tid; i < 2000; i += NT) {
            float4 v = o[i];
            v.x -= z; v.y -= z; v.z -= z; v.w -= z;
            o[i] = v;
        }
    }
}

// ---------------------------------------------------------------------------
extern "C" void kernel_launch(void* const* d_in, const int* in_sizes, int n_in,
                              void* d_out, int out_size, void* d_ws, size_t ws_size,
                              hipStream_t stream) {
    const float* enc       = (const float*)d_in[0];
    const float* emb       = (const float*)d_in[1];
    const float* w_ih      = (const float*)d_in[2];
    const float* w_hh      = (const float*)d_in[3];
    const float* b_ih      = (const float*)d_in[4];
    const float* b_hh      = (const float*)d_in[5];
    const float* conv_w    = (const float*)d_in[6];
    const float* conv_b    = (const float*)d_in[7];
    const float* attn_W    = (const float*)d_in[8];
    const float* attn_V    = (const float*)d_in[9];
    const float* attn_fc_w = (const float*)d_in[10];
    const float* attn_fc_b = (const float*)d_in[11];
    const float* attn_b    = (const float*)d_in[12];
    const float* fc_w      = (const float*)d_in[13];
    const float* fc_b      = (const float*)d_in[14];

    float* ws   = (float*)d_ws;
    float* Vv   = ws;                         // 4,915,200
    float* Z    = Vv + 4915200;               // 25,984 zeros (h0|ctx0|aw0)
    float* hv   = Z + 25984;                  // 64 x 8192
    float* cv   = hv + 524288;                // 64 x 8192
    float* wqv  = cv + 524288;                // 64 x 8192
    float* scv  = wqv + 524288;               // 64 x 9600
    float* awv  = scv + 614400;               // 64 x 9600
    float* pav  = awv + 614400;               // 64 x 16384
    float* logZ = pav + 1048576;              // 1024
    int*   cnt  = (int*)(logZ + 1024);        // 1024 ints
    float* dout = (float*)d_out;

    hipMemsetAsync(Z, 0, 25984 * sizeof(float), stream);
    hipMemsetAsync(cnt, 0, 1024 * sizeof(int), stream);

    k_vv<<<dim3(640), dim3(256), 0, stream>>>(enc, attn_V, Vv);

    void* args[] = {(void*)&enc, (void*)&emb, (void*)&w_ih, (void*)&w_hh,
                    (void*)&b_ih, (void*)&b_hh, (void*)&conv_w, (void*)&conv_b,
                    (void*)&attn_W, (void*)&attn_fc_w, (void*)&attn_fc_b,
                    (void*)&attn_b, (void*)&fc_w, (void*)&fc_b, (void*)&Vv,
                    (void*)&Z, (void*)&hv, (void*)&cv, (void*)&wqv, (void*)&scv,
                    (void*)&awv, (void*)&pav, (void*)&logZ, (void*)&cnt,
                    (void*)&dout};
    hipLaunchCooperativeKernel(reinterpret_cast<void*>(mega),
                               dim3(NG), dim3(NT), args, 0, stream);
}

// Round 11
// 8752.769 us; speedup vs baseline: 1.0110x; 1.0110x over previous
//
#include <hip/hip_runtime.h>
#include <math.h>

#define NG 256        // grid blocks (1 per CU)
#define NT 1024       // threads per block -> 16 waves/CU (4/SIMD)
#define NLOGW 250     // logits blocks (32 vocab rows each)

// Mutable cross-block state: producers write LLC-direct (sc0 sc1). Buffers
// are write-once per launch (64-step versioned) -> consumers use plain cached
// vector loads (first touch post-barrier; AQL acquire invalidates at launch).
__device__ __forceinline__ void stc(float* p, float v) {
    __hip_atomic_store(p, v, __ATOMIC_RELAXED, __HIP_MEMORY_SCOPE_AGENT);
}

// Round-5 barrier (best measured): 16 arrival lines -> c1 -> go, throttled spin.
__device__ __forceinline__ void gbar(int* cnt, int epoch, int g, int tid) {
    __syncthreads();
    if (tid == 0) {
        int* c0 = cnt + ((g & 15) << 5);
        int* c1 = cnt + 512;
        int* go = cnt + 576;
        int r = __hip_atomic_fetch_add(c0, 1, __ATOMIC_RELAXED,
                                       __HIP_MEMORY_SCOPE_AGENT);
        if (r == (epoch << 4) - 1) {
            int r2 = __hip_atomic_fetch_add(c1, 1, __ATOMIC_RELAXED,
                                            __HIP_MEMORY_SCOPE_AGENT);
            if (r2 == (epoch << 4) - 1)
                __hip_atomic_store(go, epoch, __ATOMIC_RELAXED,
                                   __HIP_MEMORY_SCOPE_AGENT);
        }
        int it = 0;
        while (__hip_atomic_load(go, __ATOMIC_RELAXED,
                                 __HIP_MEMORY_SCOPE_AGENT) < epoch)
            if (++it > 4) __builtin_amdgcn_s_sleep(8);
    }
    __syncthreads();
}

__device__ __forceinline__ void merge3(float& M, float& S, float& I,
                                       float m, float se, float ii) {
    if (m > M)       { S = S * expf(M - m) + se; M = m; I = ii; }
    else if (m == M) { S += se; if (ii < I) I = ii; }
    else             { S += se * expf(m - M); }
}

// ---------------------------------------------------------------------------
// Vv[b,t,a] = sum_d enc[b,t,d] * attn_V[a,d]   (one-time precompute)
// ---------------------------------------------------------------------------
__global__ __launch_bounds__(256) void k_vv(const float* __restrict__ enc,
                                            const float* __restrict__ attn_V,
                                            float* __restrict__ Vv) {
    int wg = blockIdx.x;
    int b = wg / 40, t0 = (wg % 40) * 15;
    int tid = threadIdx.x;
    __shared__ __align__(16) float encL[15][512];
    for (int i = tid; i < 15 * 512; i += 256) {
        int tl = i >> 9, d = i & 511;
        encL[tl][d] = enc[((size_t)(b * 600) + (t0 + tl)) * 512 + d];
    }
    __syncthreads();
    for (int half = 0; half < 2; ++half) {
        int a = tid + half * 256;
        const float4* wrow = reinterpret_cast<const float4*>(attn_V + (size_t)a * 512);
        float acc[15];
#pragma unroll
        for (int tl = 0; tl < 15; ++tl) acc[tl] = 0.f;
        for (int k = 0; k < 128; ++k) {
            float4 w = wrow[k];
#pragma unroll
            for (int tl = 0; tl < 15; ++tl) {
                float4 x = reinterpret_cast<const float4*>(&encL[tl][0])[k];
                acc[tl] += w.x * x.x + w.y * x.y + w.z * x.z + w.w * x.w;
            }
        }
        for (int tl = 0; tl < 15; ++tl)
            Vv[((size_t)(b * 600) + (t0 + tl)) * 512 + a] = acc[tl];
    }
}

// ---------------------------------------------------------------------------
// Persistent kernel. Block g: bg=g&15 (batch), sc16=g>>4 (t-chunk / e-slice /
// a-chunk / vocab-chunk). LDS holds block's Vv slice + enc slice permanently.
// ---------------------------------------------------------------------------
__global__ __launch_bounds__(NT, 1) void mega(
    const float* __restrict__ enc, const float* __restrict__ emb,
    const float* __restrict__ w_ih, const float* __restrict__ w_hh,
    const float* __restrict__ b_ih, const float* __restrict__ b_hh,
    const float* __restrict__ conv_w, const float* __restrict__ conv_b,
    const float* __restrict__ attn_W, const float* __restrict__ attn_fc_w,
    const float* __restrict__ attn_fc_b, const float* __restrict__ attn_b,
    const float* __restrict__ fc_w, const float* __restrict__ fc_b,
    const float* __restrict__ Vv, const float* __restrict__ Z,
    float* hv, float* cv, float* wqv, float* scv, float* awv, float* pav,
    float* logZ, int* cnt, float* dout)
{
    const int g = blockIdx.x;
    const int tid = threadIdx.x;
    const int bg = g & 15;
    const int sc16 = g >> 4;
    const int lane = tid & 63;
    int ep = 0;

    __shared__ __align__(16) float VvL[38 * 512];    // 77,824 B persistent
    __shared__ __align__(16) float encL2[600 * 32];  // 76,800 B persistent
    __shared__ __align__(16) float scr[1024];        // pb/red/bridge scratch
    __shared__ float tokf[16];
    __shared__ float wredM[16], wredS[16];

    // ---- one-time LDS residency fill ----
    const int t0 = sc16 * 38;
    for (int idx = tid; idx < 38 * 128; idx += NT) {
        int tl = idx >> 7, k4 = idx & 127;
        if (t0 + tl < 600)
            ((float4*)VvL)[idx] =
                ((const float4*)(Vv + ((size_t)bg * 600 + t0 + tl) * 512))[k4];
    }
    for (int idx = tid; idx < 600 * 8; idx += NT) {
        int t = idx >> 3, k4 = idx & 7;
        ((float4*)encL2)[idx] =
            ((const float4*)(enc + ((size_t)bg * 600 + t) * 512 + sc16 * 32))[k4];
    }
    const float fcb = attn_fc_b[0];
    __syncthreads();

    for (int s = 0; s < 64; ++s) {
        const float* h_r   = (s == 0) ? Z         : hv + (size_t)(s - 1) * 8192;
        const float* ctx_r = (s == 0) ? Z + 8192  : cv + (size_t)(s - 1) * 8192;
        const float* aw_r  = (s == 0) ? Z + 16384 : awv + (size_t)(s - 1) * 9600;
        float* h_w   = hv  + (size_t)s * 8192;
        float* ctx_w = cv  + (size_t)s * 8192;
        float* aw_w  = awv + (size_t)s * 9600;
        float* wq_s  = wqv + (size_t)s * 8192;
        float* sc_s  = scv + (size_t)s * 9600;
        float* pa_w  = pav + (size_t)s * 16384;

        // ========== phase1: token finalize + GRU (2 h-indices/block) ==========
        {
            if (s == 0) {
                if (tid < 16) tokf[tid] = 1.0f;   // SOS
                __syncthreads();
            } else {
                const float* pa_r = pav + (size_t)(s - 1) * 16384;
                const int b = tid >> 6;          // one wave per b
                float M = -3.4e38f, S = 0.f, I = 0.f;
#pragma unroll
                for (int q = 0; q < 4; ++q) {
                    int pw = lane + (q << 6);
                    if (pw < NLOGW) {
                        const float* r = pa_r + ((size_t)pw * 16 + b) * 4;
                        merge3(M, S, I, r[0], r[1], r[2]);
                    }
                }
#pragma unroll
                for (int off = 32; off; off >>= 1)
                    merge3(M, S, I, __shfl_xor(M, off, 64),
                           __shfl_xor(S, off, 64), __shfl_xor(I, off, 64));
                if (lane == 0) {
                    tokf[b] = I;
                    if (g == 0) stc(&logZ[(s - 1) * 16 + b], M + logf(S));
                }
                __syncthreads();
            }
            // GRU: thread = (b = tid>>6, il = (tid>>5)&1, pr = tid&31)
            const int b  = tid >> 6;
            const int il = (tid >> 5) & 1;
            const int pr = tid & 31;
            const int i  = (g << 1) + il;
            const int tok = (int)tokf[b];
            float ar = 0.f, az = 0.f, axn = 0.f, ahn = 0.f;
#pragma unroll
            for (int pass = 0; pass < 3; ++pass) {
                const float* xsrc = (pass == 0) ? emb + (size_t)tok * 512
                                  : (pass == 1) ? ctx_r + (b << 9)
                                                : h_r + (b << 9);
                const float* wbase = (pass == 2) ? w_hh : w_ih;
                const size_t rl = (pass == 2) ? 512 : 1024;
                const int ko = (pass == 1) ? 512 : 0;
                const float4* xv = (const float4*)xsrc + (pr << 2);
                const float4* wr = (const float4*)(wbase + (size_t)i * rl + ko) + (pr << 2);
                const float4* wz = (const float4*)(wbase + (size_t)(512 + i) * rl + ko) + (pr << 2);
                const float4* wn = (const float4*)(wbase + (size_t)(1024 + i) * rl + ko) + (pr << 2);
                float s0 = 0.f, s1 = 0.f, s2 = 0.f;
#pragma unroll
                for (int k = 0; k < 4; ++k) {
                    float4 x = xv[k];
                    float4 a = wr[k]; s0 += a.x*x.x + a.y*x.y + a.z*x.z + a.w*x.w;
                    float4 c = wz[k]; s1 += c.x*x.x + c.y*x.y + c.z*x.z + c.w*x.w;
                    float4 d = wn[k]; s2 += d.x*x.x + d.y*x.y + d.z*x.z + d.w*x.w;
                }
                ar += s0; az += s1;
                if (pass < 2) axn += s2; else ahn += s2;
            }
#pragma unroll
            for (int off = 16; off; off >>= 1) {
                ar  += __shfl_xor(ar, off, 64);
                az  += __shfl_xor(az, off, 64);
                axn += __shfl_xor(axn, off, 64);
                ahn += __shfl_xor(ahn, off, 64);
            }
            if (pr == 0) {
                float sr  = ar + b_ih[i] + b_hh[i];
                float sz  = az + b_ih[512 + i] + b_hh[512 + i];
                float sxn = axn + b_ih[1024 + i];
                float shn = ahn + b_hh[1024 + i];
                float r = 1.f / (1.f + expf(-sr));
                float z = 1.f / (1.f + expf(-sz));
                float n = tanhf(sxn + r * shn);
                float hp = h_r[(b << 9) + i];
                stc(&h_w[(b << 9) + i], (1.f - z) * n + z * hp);
            }
        }
        gbar(cnt, ++ep, g, tid);   // h complete

        // ========== phase2: wq — 32 a's for b=bg ==========
        {
            const int al = tid >> 5, ln = tid & 31;
            const int a = (sc16 << 5) + al;
            const float4* wr = (const float4*)(attn_W + (size_t)a * 512) + (ln << 2);
            const float4* hh = (const float4*)(h_w + (bg << 9)) + (ln << 2);
            float acc = 0.f;
#pragma unroll
            for (int k = 0; k < 4; ++k) {
                float4 w = wr[k], x = hh[k];
                acc += w.x*x.x + w.y*x.y + w.z*x.z + w.w*x.w;
            }
#pragma unroll
            for (int off = 16; off; off >>= 1) acc += __shfl_xor(acc, off, 64);
            if (ln == 0) stc(&wq_s[(bg << 9) + a], acc);
        }
        gbar(cnt, ++ep, g, tid);   // wq complete

        // ========== phase3: scores — b=bg, 38 t from LDS-resident Vv ==========
        {
            const int wv = tid >> 6;            // 16 waves
            for (int tl = wv; tl < 38; tl += 16) {
                const int t = t0 + tl;
                if (t < 600) {
                    const float awm = (t > 0)   ? aw_r[bg * 600 + t - 1] : 0.f;
                    const float aw0 = aw_r[bg * 600 + t];
                    const float awp = (t < 599) ? aw_r[bg * 600 + t + 1] : 0.f;
                    const float* vv = VvL + tl * 512;
                    float acc = 0.f;
#pragma unroll
                    for (int q = 0; q < 8; ++q) {
                        const int a = lane + (q << 6);
                        float uu = wq_s[(bg << 9) + a] + vv[a]
                                 + conv_b[a] + attn_b[a]
                                 + conv_w[a * 3] * awm
                                 + conv_w[a * 3 + 1] * aw0
                                 + conv_w[a * 3 + 2] * awp;
                        acc += tanhf(uu) * attn_fc_w[a];
                    }
#pragma unroll
                    for (int off = 32; off; off >>= 1) acc += __shfl_xor(acc, off, 64);
                    if (lane == 0) stc(&sc_s[bg * 600 + t], acc + fcb);
                }
            }
        }
        gbar(cnt, ++ep, g, tid);   // scores complete

        // ========== phase4: softmax (redundant per block) + ctx e-slice ==========
        {
            float* pb = scr;
            float lm = -3.4e38f;
            if (tid < 600) {
                float v = sc_s[bg * 600 + tid];
                pb[tid] = v;
                lm = v;
            }
#pragma unroll
            for (int off = 32; off; off >>= 1) lm = fmaxf(lm, __shfl_xor(lm, off, 64));
            if (lane == 0) wredM[tid >> 6] = lm;
            __syncthreads();
            float M = wredM[0];
#pragma unroll
            for (int q = 1; q < 16; ++q) M = fmaxf(M, wredM[q]);
            float lsum = 0.f;
            if (tid < 600) {
                float e = expf(pb[tid] - M);
                pb[tid] = e;
                lsum = e;
            }
#pragma unroll
            for (int off = 32; off; off >>= 1) lsum += __shfl_xor(lsum, off, 64);
            if (lane == 0) wredS[tid >> 6] = lsum;
            __syncthreads();
            float S = 0.f;
#pragma unroll
            for (int q = 0; q < 16; ++q) S += wredS[q];
            const float invS = 1.f / S;
            if (sc16 == 0 && tid < 600)
                stc(&aw_w[bg * 600 + tid], pb[tid] * invS);
            const int tg = tid >> 5, l32 = tid & 31;   // tg in [0,32)
            float acc = 0.f;
            for (int t = tg; t < 600; t += 32)
                acc += pb[t] * encL2[t * 32 + l32];
            __syncthreads();                 // pb dead; reuse scr
            scr[(tg << 5) + l32] = acc;
            __syncthreads();
            if (tg == 0) {
                float a2 = 0.f;
#pragma unroll
                for (int q = 0; q < 32; ++q) a2 += scr[(q << 5) + l32];
                stc(&ctx_w[(bg << 9) + (sc16 << 5) + l32], a2 * invS);
            }
        }
        gbar(cnt, ++ep, g, tid);   // ctx complete

        // ========== phase5: logits, split-K (hf0: h-part, hf1: ctx-part) ======
        {
            const int bb = tid & 15;
            const int jj = (tid >> 4) & 31;
            const int hf = tid >> 9;
            const int v = (g << 5) + jj;
            float* bridge = scr;             // [512]
            float* wpart  = scr + 512;       // [8*16*3]
            float part = 0.f;
            if (g < NLOGW) {
                const float4* wrow = (const float4*)(fc_w + (size_t)v * 1024) + (hf << 7);
                const float4* xrow = (const float4*)((hf ? ctx_w : h_w) + (bb << 9));
                float a0 = 0.f, a1 = 0.f;
#pragma unroll 4
                for (int k = 0; k < 128; k += 2) {
                    float4 w = wrow[k],     x = xrow[k];
                    float4 w2 = wrow[k + 1], x2 = xrow[k + 1];
                    a0 += w.x*x.x + w.y*x.y + w.z*x.z + w.w*x.w;
                    a1 += w2.x*x2.x + w2.y*x2.y + w2.z*x2.z + w2.w*x2.w;
                }
                part = a0 + a1;
            }
            if (hf == 0 && g < NLOGW) bridge[(jj << 4) + bb] = part;
            __syncthreads();
            float M = -3.4e38f, S = 0.f, I = 0.f;
            if (hf == 1 && g < NLOGW) {
                float acc = part + bridge[(jj << 4) + bb] + fc_b[v];
                dout[((size_t)bb * 64 + s) * 8000 + v] = acc;   // plain store
                M = acc; S = 1.f; I = (float)v;
            }
            merge3(M, S, I, __shfl_xor(M, 16, 64), __shfl_xor(S, 16, 64),
                   __shfl_xor(I, 16, 64));
            merge3(M, S, I, __shfl_xor(M, 32, 64), __shfl_xor(S, 32, 64),
                   __shfl_xor(I, 32, 64));
            if (hf == 1 && g < NLOGW && lane < 16) {
                float* a3 = wpart + ((((tid >> 6) - 8) << 4) + lane) * 3;
                a3[0] = M; a3[1] = S; a3[2] = I;
            }
            __syncthreads();
            if (tid < 16 && g < NLOGW) {
                float M2 = -3.4e38f, S2 = 0.f, I2 = 0.f;
#pragma unroll
                for (int w8 = 0; w8 < 8; ++w8) {
                    const float* a3 = wpart + ((w8 << 4) + tid) * 3;
                    merge3(M2, S2, I2, a3[0], a3[1], a3[2]);
                }
                float* pr = pa_w + ((size_t)g * 16 + tid) * 4;
                stc(pr, M2); stc(pr + 1, S2); stc(pr + 2, I2);
            }
        }
        gbar(cnt, ++ep, g, tid);   // partials complete
    }

    // ---- final logZ (s=63) ----
    if (g == 0) {
        const float* pa_r = pav + (size_t)63 * 16384;
        const int b = tid >> 6;
        float M = -3.4e38f, S = 0.f, I = 0.f;
#pragma unroll
        for (int q = 0; q < 4; ++q) {
            int pw = lane + (q << 6);
            if (pw < NLOGW) {
                const float* r = pa_r + ((size_t)pw * 16 + b) * 4;
                merge3(M, S, I, r[0], r[1], r[2]);
            }
        }
#pragma unroll
        for (int off = 32; off; off >>= 1)
            merge3(M, S, I, __shfl_xor(M, off, 64),
                   __shfl_xor(S, off, 64), __shfl_xor(I, off, 64));
        if (lane == 0) stc(&logZ[63 * 16 + b], M + logf(S));
    }
    gbar(cnt, ++ep, g, tid);
    // ---- normalize: each block normalizes ONLY the rows it wrote ----
    if (g < NLOGW) {
        for (int idx = tid; idx < 32768; idx += NT) {
            int j = idx & 31, s2 = (idx >> 5) & 63, bb2 = idx >> 11;
            size_t off = ((size_t)bb2 * 64 + s2) * 8000 + (g << 5) + j;
            dout[off] -= logZ[s2 * 16 + bb2];
        }
    }
}

// ---------------------------------------------------------------------------
extern "C" void kernel_launch(void* const* d_in, const int* in_sizes, int n_in,
                              void* d_out, int out_size, void* d_ws, size_t ws_size,
                              hipStream_t stream) {
    const float* enc       = (const float*)d_in[0];
    const float* emb       = (const float*)d_in[1];
    const float* w_ih      = (const float*)d_in[2];
    const float* w_hh      = (const float*)d_in[3];
    const float* b_ih      = (const float*)d_in[4];
    const float* b_hh      = (const float*)d_in[5];
    const float* conv_w    = (const float*)d_in[6];
    const float* conv_b    = (const float*)d_in[7];
    const float* attn_W    = (const float*)d_in[8];
    const float* attn_V    = (const float*)d_in[9];
    const float* attn_fc_w = (const float*)d_in[10];
    const float* attn_fc_b = (const float*)d_in[11];
    const float* attn_b    = (const float*)d_in[12];
    const float* fc_w      = (const float*)d_in[13];
    const float* fc_b      = (const float*)d_in[14];

    float* ws   = (float*)d_ws;
    float* Vv   = ws;                         // 4,915,200
    float* Z    = Vv + 4915200;               // 25,984 zeros (h0|ctx0|aw0)
    float* hv   = Z + 25984;                  // 64 x 8192
    float* cv   = hv + 524288;                // 64 x 8192
    float* wqv  = cv + 524288;                // 64 x 8192
    float* scv  = wqv + 524288;               // 64 x 9600
    float* awv  = scv + 614400;               // 64 x 9600
    float* pav  = awv + 614400;               // 64 x 16384
    float* logZ = pav + 1048576;              // 1024
    int*   cnt  = (int*)(logZ + 1024);        // 1024 ints
    float* dout = (float*)d_out;

    hipMemsetAsync(Z, 0, 25984 * sizeof(float), stream);
    hipMemsetAsync(cnt, 0, 1024 * sizeof(int), stream);

    k_vv<<<dim3(640), dim3(256), 0, stream>>>(enc, attn_V, Vv);

    void* args[] = {(void*)&enc, (void*)&emb, (void*)&w_ih, (void*)&w_hh,
                    (void*)&b_ih, (void*)&b_hh, (void*)&conv_w, (void*)&conv_b,
                    (void*)&attn_W, (void*)&attn_fc_w, (void*)&attn_fc_b,
                    (void*)&attn_b, (void*)&fc_w, (void*)&fc_b, (void*)&Vv,
                    (void*)&Z, (void*)&hv, (void*)&cv, (void*)&wqv, (void*)&scv,
                    (void*)&awv, (void*)&pav, (void*)&logZ, (void*)&cnt,
                    (void*)&dout};
    hipLaunchCooperativeKernel(reinterpret_cast<void*>(mega),
                               dim3(NG), dim3(NT), args, 0, stream);
}